// Round 7
// baseline (170.227 us; speedup 1.0000x reference)
//
#include <hip/hip_runtime.h>
#include <math.h>

#define BATCH 8192
#define DIM   128
#define E1    256
#define E2    128
#define NBLK  512

// output float offsets (x_hat, adj, mu, lv concatenated)
#define OUT_XHAT 0
#define OUT_ADJ  (BATCH*DIM)                 // 1048576
#define OUT_MU   (OUT_ADJ + DIM*DIM)         // 1064960
#define OUT_LV   (OUT_MU + BATCH*DIM)        // 2113536

// workspace BYTE offsets (frag-linear bf16 weight images + small f32 blocks)
#define W1F   0u          // 32768 bf16
#define W2F   65536u      // 32768 bf16
#define WMUF  131072u     // 16384 bf16
#define WLVF  163840u     // 16384 bf16
#define AHF   196608u     // 16384 bf16
#define COEF  229376u     // f32[8]: a1,a3,a5,s_safe
#define VBUF  229408u     // f32[96]: v[32], bg1[32], w2[32]
#define CNT_OFF 229888u   // u32 grid-barrier counter (memset to 0 per launch)

typedef __attribute__((ext_vector_type(8))) short s8v;   // 8 bf16 (4 VGPR)
typedef __attribute__((ext_vector_type(4))) float f4v;   // MFMA accumulator
#define MFMA(a, b, c) __builtin_amdgcn_mfma_f32_16x16x32_bf16(a, b, c, 0, 0, 0)

__device__ __forceinline__ ushort f2bf(float f) {        // RNE f32 -> bf16
    uint u = __float_as_uint(f);
    u += 0x7fffu + ((u >> 16) & 1u);
    return (ushort)(u >> 16);
}
__device__ __forceinline__ float bf2f(ushort u) {
    return __uint_as_float((uint)u << 16);
}

// LDS union: graph phase (block 48) needs 35.8 KB; fused phase 16.4 KB.
union __attribute__((aligned(16))) SMem {
    struct { ushort bufA[2048]; ushort bufB[4096]; ushort bufC[2048]; float vls[96]; } f;
    struct { ushort gsm[16384]; float aux[768]; } g;   // bf16 adjacency image
};

// ---------------------------------------------------------------------------
// Single kernel. Pre-barrier: blocks 0-47 convert weights -> frag-linear bf16
// (1 uint4/thread); block 48 computes adj/a_hat-frags/coefs; ALL blocks stage
// their x tile + prefetch eps. Manual device-scope grid barrier. Post-barrier:
// fused encoder + GCN decoder (identical to round-6 fused body).
// Fragment-linear layout for a K x N matrix: elem ((nt*nKs+ks)*64 + l)*8 + j
// stores W[ks*32 + (l>>4)*8 + j][nt*16 + (l&15)].
// ---------------------------------------------------------------------------
__global__ __launch_bounds__(256, 3) void mono_kernel(
    const float* __restrict__ x,   const float* __restrict__ eps,
    const float* __restrict__ W1,  const float* __restrict__ b1,
    const float* __restrict__ W2,  const float* __restrict__ b2,
    const float* __restrict__ Wmu, const float* __restrict__ bmu,
    const float* __restrict__ Wlv, const float* __restrict__ blv,
    const float* __restrict__ logits, const float* __restrict__ Wf,
    const float* __restrict__ Wg1, const float* __restrict__ bg1,
    const float* __restrict__ Wg2, const float* __restrict__ bg2p,
    const int* __restrict__ itp,
    float* __restrict__ out, char* __restrict__ wsb)
{
    __shared__ SMem sm;
    const int t = threadIdx.x;
    const int lane = t & 63, wid = t >> 6;
    const int fr = lane & 15, fq = lane >> 4;       // C/D: col=fr, rows=fq*4+q
    const int bid = (int)blockIdx.x;
    const int row0 = bid * 16;

    // ---- eps prefetch in C-fragment order (HBM latency hides under prep) ----
    float epr[2][4];
    {
        const float* eb = eps + (size_t)(row0 + fq * 4) * DIM + wid * 32 + fr;
        #pragma unroll
        for (int n = 0; n < 2; ++n)
            #pragma unroll
            for (int q = 0; q < 4; ++q)
                epr[n][q] = eb[q * DIM + n * 16];
    }

    // ================= pre-barrier prep =================
    if (bid < 48) {
        // ---- weight fragment conversion: tid in [0,12288), one uint4 each ----
        const int tid = bid * 256 + t;
        const float* W; ushort* dst; int e, N_, ksLog;
        if (tid < 4096)       { W = W1;  dst = (ushort*)(wsb + W1F);  e = tid * 8;           N_ = 256; ksLog = 2; }
        else if (tid < 8192)  { W = W2;  dst = (ushort*)(wsb + W2F);  e = (tid - 4096) * 8;  N_ = 128; ksLog = 3; }
        else if (tid < 10240) { W = Wmu; dst = (ushort*)(wsb + WMUF); e = (tid - 8192) * 8;  N_ = 128; ksLog = 2; }
        else                  { W = Wlv; dst = (ushort*)(wsb + WLVF); e = (tid - 10240) * 8; N_ = 128; ksLog = 2; }
        const int frag = e >> 9, l = (e >> 3) & 63;
        const int nt = frag >> ksLog, ks = frag & ((1 << ksLog) - 1);
        const int k0 = ks * 32 + ((l >> 4) << 3);
        const int n  = (nt << 4) + (l & 15);
        uint pk[4];
        #pragma unroll
        for (int jj = 0; jj < 4; ++jj) {
            ushort lo = f2bf(W[(k0 + 2 * jj) * N_ + n]);
            ushort hi = f2bf(W[(k0 + 2 * jj + 1) * N_ + n]);
            pk[jj] = (uint)lo | ((uint)hi << 16);
        }
        *(uint4*)(dst + e) = make_uint4(pk[0], pk[1], pk[2], pk[3]);
    } else if (bid == 48) {
        // ---- graph block: adj, a_hat frags, tanh-poly coefficients ----
        const int it = itp[0];
        {
            const int j = t & 127, rh = t >> 7;        // column j, row-half
            float dp = 0.0f;
            for (int i = rh * 64; i < rh * 64 + 64; ++i) {
                float l = logits[i * DIM + j];
                float gv = 1.0f / (1.0f + expf(-l));   // precise: threshold boundary
                if (i == j) gv = 1.0f;
                if (it > 50 && gv < 0.1f) gv = 0.0f;
                out[OUT_ADJ + i * DIM + j] = gv;       // f32 adj (exact path)
                sm.g.gsm[i * DIM + j] = f2bf(gv);      // bf16 image for ahat
                if (gv > 0.0f) dp += 1.0f;
            }
            sm.g.aux[rh * 128 + j] = dp;               // partial col sums (d_in)
        }
        __syncthreads();
        if (t < 128) {
            float d = sm.g.aux[t] + sm.g.aux[128 + t];
            sm.g.aux[512 + t] = 1.0f / sqrtf(fmaxf(d, 1.0f));   // rin[j]
        }
        __syncthreads();
        {
            const int i = t & 127, ch = t >> 7;        // row i, col-half
            float dp = 0.0f;
            for (int c = ch * 64; c < ch * 64 + 64; ++c)
                if (sm.g.gsm[i * DIM + c] != 0) dp += 1.0f;  // bf16 nonzero (vals >= 0)
            sm.g.aux[256 + ch * 128 + i] = dp;         // partial row sums (d_out)
        }
        __syncthreads();
        if (t < 128) {
            float d = sm.g.aux[256 + t] + sm.g.aux[384 + t];
            sm.g.aux[640 + t] = 1.0f / sqrtf(fmaxf(d, 1.0f));   // rdout[i]
        }
        if (t < 32) {                                  // v = W_feat @ W_g1
            float acc = 0.0f;
            for (int k = 0; k < 64; ++k) acc = fmaf(Wf[k], Wg1[k * 32 + t], acc);
            sm.g.aux[t] = acc;                         // col partials dead now
            float* vb = (float*)(wsb + VBUF);
            vb[t] = acc; vb[32 + t] = bg1[t]; vb[64 + t] = Wg2[t];
        }
        __syncthreads();
        if (t == 0) {                                  // tanh poly coefficients
            float a1 = 0, a3 = 0, a5 = 0, vmax = 0, bmax = 0;
            for (int c = 0; c < 32; ++c) {
                float v = sm.g.aux[c], w = Wg2[c], v2 = v * v;
                a1 += w * v;
                a3 -= w * v * v2 * (1.0f / 3.0f);
                a5 += w * v * v2 * v2 * (2.0f / 15.0f);
                vmax = fmaxf(vmax, fabsf(v));
                bmax = fmaxf(bmax, fabsf(bg1[c]));
            }
            float* cf = (float*)(wsb + COEF);
            cf[0] = a1; cf[1] = a3; cf[2] = a5;
            cf[3] = (bmax == 0.0f) ? 0.2f / fmaxf(vmax, 1e-30f) : -1.0f;
        }
        {                                              // ahat frags (K=N=128)
            ushort* ahf = (ushort*)(wsb + AHF);
            #pragma unroll
            for (int c = 0; c < 8; ++c) {
                int e = (t + c * 256) * 8;
                int frag = e >> 9, l = (e >> 3) & 63;
                int nt = frag >> 2, ks = frag & 3;
                int k0 = ks * 32 + ((l >> 4) << 3);
                int n  = (nt << 4) + (l & 15);
                float rj = sm.g.aux[512 + n];
                uint pk[4];
                #pragma unroll
                for (int jj = 0; jj < 4; ++jj) {
                    int r0 = k0 + 2 * jj;
                    float g0 = bf2f(sm.g.gsm[r0 * DIM + n])       * sm.g.aux[640 + r0]     * rj;
                    float g1 = bf2f(sm.g.gsm[(r0 + 1) * DIM + n]) * sm.g.aux[640 + r0 + 1] * rj;
                    pk[jj] = (uint)f2bf(g0) | ((uint)f2bf(g1) << 16);
                }
                *(uint4*)(ahf + e) = make_uint4(pk[0], pk[1], pk[2], pk[3]);
            }
        }
        __syncthreads();   // gsm reads done before x-stage overwrites the union
    }

    // ---- stage x tile -> bf16 fragments (all blocks; block 48 after graph) ----
    {
        const int r = t & 15, g = (t >> 4) & 3, ks = t >> 6;
        const float* src = x + (size_t)(row0 + r) * DIM + ks * 32 + g * 8;
        float4 u0 = *(const float4*)src;
        float4 u1 = *(const float4*)(src + 4);
        uint p0 = (uint)f2bf(u0.x) | ((uint)f2bf(u0.y) << 16);
        uint p1 = (uint)f2bf(u0.z) | ((uint)f2bf(u0.w) << 16);
        uint p2 = (uint)f2bf(u1.x) | ((uint)f2bf(u1.y) << 16);
        uint p3 = (uint)f2bf(u1.z) | ((uint)f2bf(u1.w) << 16);
        *(uint4*)&sm.f.bufA[(ks * 64 + g * 16 + r) * 8] = make_uint4(p0, p1, p2, p3);
    }

    // ---- manual device-scope grid barrier (agent ACQ_REL -> L2 wb/inv) ----
    {
        uint* cnt = (uint*)(wsb + CNT_OFF);
        __syncthreads();                       // block's prep + x-stage done
        if (t == 0) {
            __hip_atomic_fetch_add(cnt, 1u, __ATOMIC_ACQ_REL, __HIP_MEMORY_SCOPE_AGENT);
            int spins = 0;
            while (__hip_atomic_load(cnt, __ATOMIC_ACQUIRE, __HIP_MEMORY_SCOPE_AGENT)
                   < (uint)NBLK) {
                __builtin_amdgcn_s_sleep(2);
                if (++spins > (1 << 22)) break;    // failsafe: fail visibly, never hang
            }
        }
        __syncthreads();
    }

    // ================= fused encoder + decoder =================
    if (t < 96) sm.f.vls[t] = ((const float*)(wsb + VBUF))[t];

    // ---- layer 1: h1 = relu(x@W1+b1), N=256, wave w -> cols [w*64, +64) ----
    {
        const ushort* w1f = (const ushort*)(wsb + W1F);
        f4v acc[4] = {{0,0,0,0},{0,0,0,0},{0,0,0,0},{0,0,0,0}};
        #pragma unroll
        for (int ks = 0; ks < 4; ++ks) {
            s8v a = *(const s8v*)&sm.f.bufA[(ks * 64 + lane) * 8];
            #pragma unroll
            for (int n = 0; n < 4; ++n) {
                s8v b = *(const s8v*)&w1f[(((wid * 4 + n) * 4 + ks) * 64 + lane) * 8];
                acc[n] = MFMA(a, b, acc[n]);
            }
        }
        __syncthreads();            // all x-frag reads done (bufA reused for z)
        #pragma unroll
        for (int n = 0; n < 4; ++n) {
            int col = wid * 64 + n * 16 + fr;       // k-index for layer 2
            float bb = b1[col];
            int base = (col >> 5) * 512 + (((col >> 3) & 3) * 16) * 8 + (col & 7);
            #pragma unroll
            for (int q = 0; q < 4; ++q)
                sm.f.bufB[base + (fq * 4 + q) * 8] = f2bf(fmaxf(acc[n][q] + bb, 0.0f));
        }
    }
    __syncthreads();

    // ---- layer 2: h2 = relu(h1@W2+b2), K=256 N=128, wave -> cols [w*32,+32) ----
    {
        const ushort* w2f = (const ushort*)(wsb + W2F);
        f4v acc[2] = {{0,0,0,0},{0,0,0,0}};
        #pragma unroll
        for (int ks = 0; ks < 8; ++ks) {
            s8v a = *(const s8v*)&sm.f.bufB[(ks * 64 + lane) * 8];
            #pragma unroll
            for (int n = 0; n < 2; ++n) {
                s8v b = *(const s8v*)&w2f[(((wid * 2 + n) * 8 + ks) * 64 + lane) * 8];
                acc[n] = MFMA(a, b, acc[n]);
            }
        }
        #pragma unroll
        for (int n = 0; n < 2; ++n) {
            int col = wid * 32 + n * 16 + fr;
            float bb = b2[col];
            int base = (col >> 5) * 512 + (((col >> 3) & 3) * 16) * 8 + (col & 7);
            #pragma unroll
            for (int q = 0; q < 4; ++q)
                sm.f.bufC[base + (fq * 4 + q) * 8] = f2bf(fmaxf(acc[n][q] + bb, 0.0f));
        }
    }
    __syncthreads();

    // ---- mu / lv + z (fused; z frags restaged into bufA) ----
    {
        const ushort* wmf = (const ushort*)(wsb + WMUF);
        const ushort* wlf = (const ushort*)(wsb + WLVF);
        f4v am[2] = {{0,0,0,0},{0,0,0,0}}, al[2] = {{0,0,0,0},{0,0,0,0}};
        #pragma unroll
        for (int ks = 0; ks < 4; ++ks) {
            s8v a = *(const s8v*)&sm.f.bufC[(ks * 64 + lane) * 8];
            #pragma unroll
            for (int n = 0; n < 2; ++n) {
                int fi = (((wid * 2 + n) * 4 + ks) * 64 + lane) * 8;
                s8v bm = *(const s8v*)&wmf[fi];
                s8v bl = *(const s8v*)&wlf[fi];
                am[n] = MFMA(a, bm, am[n]);
                al[n] = MFMA(a, bl, al[n]);
            }
        }
        #pragma unroll
        for (int n = 0; n < 2; ++n) {
            int col = wid * 32 + n * 16 + fr;
            float bm = bmu[col], bl = blv[col];
            int base = (col >> 5) * 512 + (((col >> 3) & 3) * 16) * 8 + (col & 7);
            #pragma unroll
            for (int q = 0; q < 4; ++q) {
                int grow = row0 + fq * 4 + q;
                float mu = am[n][q] + bm;
                float lv = al[n][q] + bl;
                out[OUT_MU + grow * DIM + col] = mu;
                out[OUT_LV + grow * DIM + col] = lv;
                float z = fmaf(epr[n][q], __expf(0.5f * lv), mu);
                sm.f.bufA[base + (fq * 4 + q) * 8] = f2bf(z);   // z frags into bufA
            }
        }
    }
    __syncthreads();

    // ---- decoder: s = z@ahat ; t = P(s) ; xhat = t@ahat + bg2 ----
    const ushort* ahf = (const ushort*)(wsb + AHF);
    const float* cf = (const float*)(wsb + COEF);
    const float a1 = cf[0], a3 = cf[1], a5 = cf[2], ssafe = cf[3];

    f4v sa[2] = {{0,0,0,0},{0,0,0,0}};
    #pragma unroll
    for (int ks = 0; ks < 4; ++ks) {
        s8v a = *(const s8v*)&sm.f.bufA[(ks * 64 + lane) * 8];
        #pragma unroll
        for (int n = 0; n < 2; ++n) {
            s8v b = *(const s8v*)&ahf[(((wid * 2 + n) * 4 + ks) * 64 + lane) * 8];
            sa[n] = MFMA(a, b, sa[n]);
        }
    }
    __syncthreads();                 // bufB free (layer-2 reads long done)

    #pragma unroll
    for (int n = 0; n < 2; ++n) {
        int k2 = wid * 32 + n * 16 + fr;
        int base = (k2 >> 5) * 512 + (((k2 >> 3) & 3) * 16) * 8 + (k2 & 7);
        #pragma unroll
        for (int q = 0; q < 4; ++q) {
            float s = sa[n][q];
            float tv;
            if (fabsf(s) < ssafe) {                 // poly path (always, in practice)
                float s2 = s * s;
                tv = s * fmaf(s2, fmaf(s2, a5, a3), a1);
            } else {                                // exact fallback
                tv = 0.0f;
                for (int c = 0; c < 32; ++c)
                    tv = fmaf(sm.f.vls[64 + c],
                              tanhf(fmaf(s, sm.f.vls[c], sm.f.vls[32 + c])), tv);
            }
            sm.f.bufB[base + (fq * 4 + q) * 8] = f2bf(tv);
        }
    }
    __syncthreads();

    f4v xa[2] = {{0,0,0,0},{0,0,0,0}};
    #pragma unroll
    for (int ks = 0; ks < 4; ++ks) {
        s8v a = *(const s8v*)&sm.f.bufB[(ks * 64 + lane) * 8];
        #pragma unroll
        for (int n = 0; n < 2; ++n) {
            s8v b = *(const s8v*)&ahf[(((wid * 2 + n) * 4 + ks) * 64 + lane) * 8];
            xa[n] = MFMA(a, b, xa[n]);
        }
    }
    const float bg2v = bg2p[0];
    #pragma unroll
    for (int n = 0; n < 2; ++n) {
        int col = wid * 32 + n * 16 + fr;
        #pragma unroll
        for (int q = 0; q < 4; ++q)
            out[OUT_XHAT + (size_t)(row0 + fq * 4 + q) * DIM + col] = xa[n][q] + bg2v;
    }
}

// ---------------------------------------------------------------------------
extern "C" void kernel_launch(void* const* d_in, const int* in_sizes, int n_in,
                              void* d_out, int out_size, void* d_ws, size_t ws_size,
                              hipStream_t stream)
{
    const float* x      = (const float*)d_in[0];
    const float* eps    = (const float*)d_in[1];
    const float* W1     = (const float*)d_in[2];
    const float* b1     = (const float*)d_in[3];
    const float* W2     = (const float*)d_in[4];
    const float* b2     = (const float*)d_in[5];
    const float* Wmu    = (const float*)d_in[6];
    const float* bmu    = (const float*)d_in[7];
    const float* Wlv    = (const float*)d_in[8];
    const float* blv    = (const float*)d_in[9];
    const float* logits = (const float*)d_in[10];
    const float* Wf     = (const float*)d_in[11];
    const float* Wg1    = (const float*)d_in[12];
    const float* bg1    = (const float*)d_in[13];
    const float* Wg2    = (const float*)d_in[14];
    const float* bg2    = (const float*)d_in[15];
    const int*   itp    = (const int*)d_in[16];
    float* out = (float*)d_out;
    char* wsb  = (char*)d_ws;

    hipMemsetAsync(wsb + CNT_OFF, 0, 4, stream);     // reset barrier counter
    hipLaunchKernelGGL(mono_kernel, dim3(NBLK), dim3(256), 0, stream,
                       x, eps, W1, b1, W2, b2, Wmu, bmu, Wlv, blv,
                       logits, Wf, Wg1, bg1, Wg2, bg2, itp, out, wsb);
}

// Round 8
// 53.232 us; speedup vs baseline: 3.1979x; 3.1979x over previous
//
#include <hip/hip_runtime.h>
#include <math.h>

#define BATCH 8192
#define DIM   128
#define E1    256
#define E2    128
#define NBLK  512

// output float offsets (x_hat, adj, mu, lv concatenated)
#define OUT_XHAT 0
#define OUT_ADJ  (BATCH*DIM)                 // 1048576
#define OUT_MU   (OUT_ADJ + DIM*DIM)         // 1064960
#define OUT_LV   (OUT_MU + BATCH*DIM)        // 2113536

// workspace BYTE offsets (frag-linear bf16 weight images + small f32 blocks)
#define W1F   0u          // 32768 bf16
#define W2F   65536u      // 32768 bf16
#define WMUF  131072u     // 16384 bf16
#define WLVF  163840u     // 16384 bf16
#define AHF   196608u     // 16384 bf16
#define COEF  229376u     // f32[8]: a1,a3,a5,s_safe
#define VBUF  229408u     // f32[96]: v[32], bg1[32], w2[32]
#define CNT_OFF 230400u   // u32 grid-barrier counter (own cache line; memset 0/launch)

typedef __attribute__((ext_vector_type(8))) short s8v;   // 8 bf16 (4 VGPR)
typedef __attribute__((ext_vector_type(4))) float f4v;   // MFMA accumulator
#define MFMA(a, b, c) __builtin_amdgcn_mfma_f32_16x16x32_bf16(a, b, c, 0, 0, 0)

__device__ __forceinline__ ushort f2bf(float f) {        // RNE f32 -> bf16
    uint u = __float_as_uint(f);
    u += 0x7fffu + ((u >> 16) & 1u);
    return (ushort)(u >> 16);
}
__device__ __forceinline__ float bf2f(ushort u) {
    return __uint_as_float((uint)u << 16);
}

// LDS union: graph phase (block 48) needs 35.8 KB; fused phase 16.4 KB.
union __attribute__((aligned(16))) SMem {
    struct { ushort bufA[2048]; ushort bufB[4096]; ushort bufC[2048]; float vls[96]; } f;
    struct { ushort gsm[16384]; float aux[768]; } g;   // bf16 adjacency image
};

// ---------------------------------------------------------------------------
// Single kernel. Pre-barrier: blocks 0-47 convert weights -> frag-linear bf16;
// block 48 computes adj/a_hat-frags/coefs; ALL blocks stage x + prefetch eps.
// Grid barrier (scope-minimal): relaxed poll on device-scope counter (atomics
// bypass XCD L2 -> always fresh, NO invalidates in the loop); producers issue
// ONE system release (buffer_wbl2) before arriving; every block issues ONE
// system acquire (buffer_inv) after release -- also evicts harness-poison
// lines. Post-barrier: fused encoder + GCN decoder (round-6 body).
// ---------------------------------------------------------------------------
__global__ __launch_bounds__(256, 3) void mono_kernel(
    const float* __restrict__ x,   const float* __restrict__ eps,
    const float* __restrict__ W1,  const float* __restrict__ b1,
    const float* __restrict__ W2,  const float* __restrict__ b2,
    const float* __restrict__ Wmu, const float* __restrict__ bmu,
    const float* __restrict__ Wlv, const float* __restrict__ blv,
    const float* __restrict__ logits, const float* __restrict__ Wf,
    const float* __restrict__ Wg1, const float* __restrict__ bg1,
    const float* __restrict__ Wg2, const float* __restrict__ bg2p,
    const int* __restrict__ itp,
    float* __restrict__ out, char* __restrict__ wsb)
{
    __shared__ SMem sm;
    const int t = threadIdx.x;
    const int lane = t & 63, wid = t >> 6;
    const int fr = lane & 15, fq = lane >> 4;       // C/D: col=fr, rows=fq*4+q
    const int bid = (int)blockIdx.x;
    const int row0 = bid * 16;

    // ---- eps prefetch in C-fragment order (HBM latency hides under prep) ----
    float epr[2][4];
    {
        const float* eb = eps + (size_t)(row0 + fq * 4) * DIM + wid * 32 + fr;
        #pragma unroll
        for (int n = 0; n < 2; ++n)
            #pragma unroll
            for (int q = 0; q < 4; ++q)
                epr[n][q] = eb[q * DIM + n * 16];
    }

    // ================= pre-barrier prep =================
    if (bid < 48) {
        // ---- weight fragment conversion: tid in [0,12288), one uint4 each ----
        const int tid = bid * 256 + t;
        const float* W; ushort* dst; int e, N_, ksLog;
        if (tid < 4096)       { W = W1;  dst = (ushort*)(wsb + W1F);  e = tid * 8;           N_ = 256; ksLog = 2; }
        else if (tid < 8192)  { W = W2;  dst = (ushort*)(wsb + W2F);  e = (tid - 4096) * 8;  N_ = 128; ksLog = 3; }
        else if (tid < 10240) { W = Wmu; dst = (ushort*)(wsb + WMUF); e = (tid - 8192) * 8;  N_ = 128; ksLog = 2; }
        else                  { W = Wlv; dst = (ushort*)(wsb + WLVF); e = (tid - 10240) * 8; N_ = 128; ksLog = 2; }
        const int frag = e >> 9, l = (e >> 3) & 63;
        const int nt = frag >> ksLog, ks = frag & ((1 << ksLog) - 1);
        const int k0 = ks * 32 + ((l >> 4) << 3);
        const int n  = (nt << 4) + (l & 15);
        uint pk[4];
        #pragma unroll
        for (int jj = 0; jj < 4; ++jj) {
            ushort lo = f2bf(W[(k0 + 2 * jj) * N_ + n]);
            ushort hi = f2bf(W[(k0 + 2 * jj + 1) * N_ + n]);
            pk[jj] = (uint)lo | ((uint)hi << 16);
        }
        *(uint4*)(dst + e) = make_uint4(pk[0], pk[1], pk[2], pk[3]);
    } else if (bid == 48) {
        // ---- graph block: adj, a_hat frags, tanh-poly coefficients ----
        const int it = itp[0];
        {
            const int j = t & 127, rh = t >> 7;        // column j, row-half
            float dp = 0.0f;
            for (int i = rh * 64; i < rh * 64 + 64; ++i) {
                float l = logits[i * DIM + j];
                float gv = 1.0f / (1.0f + expf(-l));   // precise: threshold boundary
                if (i == j) gv = 1.0f;
                if (it > 50 && gv < 0.1f) gv = 0.0f;
                out[OUT_ADJ + i * DIM + j] = gv;       // f32 adj (exact path)
                sm.g.gsm[i * DIM + j] = f2bf(gv);      // bf16 image for ahat
                if (gv > 0.0f) dp += 1.0f;
            }
            sm.g.aux[rh * 128 + j] = dp;               // partial col sums (d_in)
        }
        __syncthreads();
        if (t < 128) {
            float d = sm.g.aux[t] + sm.g.aux[128 + t];
            sm.g.aux[512 + t] = 1.0f / sqrtf(fmaxf(d, 1.0f));   // rin[j]
        }
        __syncthreads();
        {
            const int i = t & 127, ch = t >> 7;        // row i, col-half
            float dp = 0.0f;
            for (int c = ch * 64; c < ch * 64 + 64; ++c)
                if (sm.g.gsm[i * DIM + c] != 0) dp += 1.0f;  // bf16 nonzero (vals >= 0)
            sm.g.aux[256 + ch * 128 + i] = dp;         // partial row sums (d_out)
        }
        __syncthreads();
        if (t < 128) {
            float d = sm.g.aux[256 + t] + sm.g.aux[384 + t];
            sm.g.aux[640 + t] = 1.0f / sqrtf(fmaxf(d, 1.0f));   // rdout[i]
        }
        if (t < 32) {                                  // v = W_feat @ W_g1
            float acc = 0.0f;
            for (int k = 0; k < 64; ++k) acc = fmaf(Wf[k], Wg1[k * 32 + t], acc);
            sm.g.aux[t] = acc;                         // col partials dead now
            float* vb = (float*)(wsb + VBUF);
            vb[t] = acc; vb[32 + t] = bg1[t]; vb[64 + t] = Wg2[t];
        }
        __syncthreads();
        if (t == 0) {                                  // tanh poly coefficients
            float a1 = 0, a3 = 0, a5 = 0, vmax = 0, bmax = 0;
            for (int c = 0; c < 32; ++c) {
                float v = sm.g.aux[c], w = Wg2[c], v2 = v * v;
                a1 += w * v;
                a3 -= w * v * v2 * (1.0f / 3.0f);
                a5 += w * v * v2 * v2 * (2.0f / 15.0f);
                vmax = fmaxf(vmax, fabsf(v));
                bmax = fmaxf(bmax, fabsf(bg1[c]));
            }
            float* cf = (float*)(wsb + COEF);
            cf[0] = a1; cf[1] = a3; cf[2] = a5;
            cf[3] = (bmax == 0.0f) ? 0.2f / fmaxf(vmax, 1e-30f) : -1.0f;
        }
        {                                              // ahat frags (K=N=128)
            ushort* ahf = (ushort*)(wsb + AHF);
            #pragma unroll
            for (int c = 0; c < 8; ++c) {
                int e = (t + c * 256) * 8;
                int frag = e >> 9, l = (e >> 3) & 63;
                int nt = frag >> 2, ks = frag & 3;
                int k0 = ks * 32 + ((l >> 4) << 3);
                int n  = (nt << 4) + (l & 15);
                float rj = sm.g.aux[512 + n];
                uint pk[4];
                #pragma unroll
                for (int jj = 0; jj < 4; ++jj) {
                    int r0 = k0 + 2 * jj;
                    float g0 = bf2f(sm.g.gsm[r0 * DIM + n])       * sm.g.aux[640 + r0]     * rj;
                    float g1 = bf2f(sm.g.gsm[(r0 + 1) * DIM + n]) * sm.g.aux[640 + r0 + 1] * rj;
                    pk[jj] = (uint)f2bf(g0) | ((uint)f2bf(g1) << 16);
                }
                *(uint4*)(ahf + e) = make_uint4(pk[0], pk[1], pk[2], pk[3]);
            }
        }
        __syncthreads();   // gsm reads done before x-stage overwrites the union
    }

    // ---- stage x tile -> bf16 fragments (all blocks; block 48 after graph) ----
    {
        const int r = t & 15, g = (t >> 4) & 3, ks = t >> 6;
        const float* src = x + (size_t)(row0 + r) * DIM + ks * 32 + g * 8;
        float4 u0 = *(const float4*)src;
        float4 u1 = *(const float4*)(src + 4);
        uint p0 = (uint)f2bf(u0.x) | ((uint)f2bf(u0.y) << 16);
        uint p1 = (uint)f2bf(u0.z) | ((uint)f2bf(u0.w) << 16);
        uint p2 = (uint)f2bf(u1.x) | ((uint)f2bf(u1.y) << 16);
        uint p3 = (uint)f2bf(u1.z) | ((uint)f2bf(u1.w) << 16);
        *(uint4*)&sm.f.bufA[(ks * 64 + g * 16 + r) * 8] = make_uint4(p0, p1, p2, p3);
    }

    // ---- grid barrier: relaxed poll + single release(producers)/acquire ----
    {
        uint* cnt = (uint*)(wsb + CNT_OFF);
        __syncthreads();                  // drains vmcnt: block's ws stores done
        if (t == 0) {
            if (bid <= 48) __threadfence_system();    // ONE wbl2: publish ws
            __hip_atomic_fetch_add(cnt, 1u, __ATOMIC_RELAXED,
                                   __HIP_MEMORY_SCOPE_AGENT);
            int spins = 0;
            while (__hip_atomic_load(cnt, __ATOMIC_RELAXED,
                                     __HIP_MEMORY_SCOPE_AGENT) < (uint)NBLK) {
                __builtin_amdgcn_s_sleep(8);
                if (++spins > (1 << 20)) break;       // failsafe: fail visibly
            }
            // ONE acquire-inv: makes producers' ws visible, evicts poison lines
            (void)__hip_atomic_load(cnt, __ATOMIC_ACQUIRE,
                                    __HIP_MEMORY_SCOPE_SYSTEM);
        }
        __syncthreads();
    }

    // ================= fused encoder + decoder =================
    if (t < 96) sm.f.vls[t] = ((const float*)(wsb + VBUF))[t];

    // ---- layer 1: h1 = relu(x@W1+b1), N=256, wave w -> cols [w*64, +64) ----
    {
        const ushort* w1f = (const ushort*)(wsb + W1F);
        f4v acc[4] = {{0,0,0,0},{0,0,0,0},{0,0,0,0},{0,0,0,0}};
        #pragma unroll
        for (int ks = 0; ks < 4; ++ks) {
            s8v a = *(const s8v*)&sm.f.bufA[(ks * 64 + lane) * 8];
            #pragma unroll
            for (int n = 0; n < 4; ++n) {
                s8v b = *(const s8v*)&w1f[(((wid * 4 + n) * 4 + ks) * 64 + lane) * 8];
                acc[n] = MFMA(a, b, acc[n]);
            }
        }
        __syncthreads();            // all x-frag reads done (bufA reused for z)
        #pragma unroll
        for (int n = 0; n < 4; ++n) {
            int col = wid * 64 + n * 16 + fr;       // k-index for layer 2
            float bb = b1[col];
            int base = (col >> 5) * 512 + (((col >> 3) & 3) * 16) * 8 + (col & 7);
            #pragma unroll
            for (int q = 0; q < 4; ++q)
                sm.f.bufB[base + (fq * 4 + q) * 8] = f2bf(fmaxf(acc[n][q] + bb, 0.0f));
        }
    }
    __syncthreads();

    // ---- layer 2: h2 = relu(h1@W2+b2), K=256 N=128, wave -> cols [w*32,+32) ----
    {
        const ushort* w2f = (const ushort*)(wsb + W2F);
        f4v acc[2] = {{0,0,0,0},{0,0,0,0}};
        #pragma unroll
        for (int ks = 0; ks < 8; ++ks) {
            s8v a = *(const s8v*)&sm.f.bufB[(ks * 64 + lane) * 8];
            #pragma unroll
            for (int n = 0; n < 2; ++n) {
                s8v b = *(const s8v*)&w2f[(((wid * 2 + n) * 8 + ks) * 64 + lane) * 8];
                acc[n] = MFMA(a, b, acc[n]);
            }
        }
        #pragma unroll
        for (int n = 0; n < 2; ++n) {
            int col = wid * 32 + n * 16 + fr;
            float bb = b2[col];
            int base = (col >> 5) * 512 + (((col >> 3) & 3) * 16) * 8 + (col & 7);
            #pragma unroll
            for (int q = 0; q < 4; ++q)
                sm.f.bufC[base + (fq * 4 + q) * 8] = f2bf(fmaxf(acc[n][q] + bb, 0.0f));
        }
    }
    __syncthreads();

    // ---- mu / lv + z (fused; z frags restaged into bufA) ----
    {
        const ushort* wmf = (const ushort*)(wsb + WMUF);
        const ushort* wlf = (const ushort*)(wsb + WLVF);
        f4v am[2] = {{0,0,0,0},{0,0,0,0}}, al[2] = {{0,0,0,0},{0,0,0,0}};
        #pragma unroll
        for (int ks = 0; ks < 4; ++ks) {
            s8v a = *(const s8v*)&sm.f.bufC[(ks * 64 + lane) * 8];
            #pragma unroll
            for (int n = 0; n < 2; ++n) {
                int fi = (((wid * 2 + n) * 4 + ks) * 64 + lane) * 8;
                s8v bm = *(const s8v*)&wmf[fi];
                s8v bl = *(const s8v*)&wlf[fi];
                am[n] = MFMA(a, bm, am[n]);
                al[n] = MFMA(a, bl, al[n]);
            }
        }
        #pragma unroll
        for (int n = 0; n < 2; ++n) {
            int col = wid * 32 + n * 16 + fr;
            float bm = bmu[col], bl = blv[col];
            int base = (col >> 5) * 512 + (((col >> 3) & 3) * 16) * 8 + (col & 7);
            #pragma unroll
            for (int q = 0; q < 4; ++q) {
                int grow = row0 + fq * 4 + q;
                float mu = am[n][q] + bm;
                float lv = al[n][q] + bl;
                out[OUT_MU + grow * DIM + col] = mu;
                out[OUT_LV + grow * DIM + col] = lv;
                float z = fmaf(epr[n][q], __expf(0.5f * lv), mu);
                sm.f.bufA[base + (fq * 4 + q) * 8] = f2bf(z);   // z frags into bufA
            }
        }
    }
    __syncthreads();

    // ---- decoder: s = z@ahat ; t = P(s) ; xhat = t@ahat + bg2 ----
    const ushort* ahf = (const ushort*)(wsb + AHF);
    const float* cf = (const float*)(wsb + COEF);
    const float a1 = cf[0], a3 = cf[1], a5 = cf[2], ssafe = cf[3];

    f4v sa[2] = {{0,0,0,0},{0,0,0,0}};
    #pragma unroll
    for (int ks = 0; ks < 4; ++ks) {
        s8v a = *(const s8v*)&sm.f.bufA[(ks * 64 + lane) * 8];
        #pragma unroll
        for (int n = 0; n < 2; ++n) {
            s8v b = *(const s8v*)&ahf[(((wid * 2 + n) * 4 + ks) * 64 + lane) * 8];
            sa[n] = MFMA(a, b, sa[n]);
        }
    }
    __syncthreads();                 // bufB free (layer-2 reads long done)

    #pragma unroll
    for (int n = 0; n < 2; ++n) {
        int k2 = wid * 32 + n * 16 + fr;
        int base = (k2 >> 5) * 512 + (((k2 >> 3) & 3) * 16) * 8 + (k2 & 7);
        #pragma unroll
        for (int q = 0; q < 4; ++q) {
            float s = sa[n][q];
            float tv;
            if (fabsf(s) < ssafe) {                 // poly path (always, in practice)
                float s2 = s * s;
                tv = s * fmaf(s2, fmaf(s2, a5, a3), a1);
            } else {                                // exact fallback
                tv = 0.0f;
                for (int c = 0; c < 32; ++c)
                    tv = fmaf(sm.f.vls[64 + c],
                              tanhf(fmaf(s, sm.f.vls[c], sm.f.vls[32 + c])), tv);
            }
            sm.f.bufB[base + (fq * 4 + q) * 8] = f2bf(tv);
        }
    }
    __syncthreads();

    f4v xa[2] = {{0,0,0,0},{0,0,0,0}};
    #pragma unroll
    for (int ks = 0; ks < 4; ++ks) {
        s8v a = *(const s8v*)&sm.f.bufB[(ks * 64 + lane) * 8];
        #pragma unroll
        for (int n = 0; n < 2; ++n) {
            s8v b = *(const s8v*)&ahf[(((wid * 2 + n) * 4 + ks) * 64 + lane) * 8];
            xa[n] = MFMA(a, b, xa[n]);
        }
    }
    const float bg2v = bg2p[0];
    #pragma unroll
    for (int n = 0; n < 2; ++n) {
        int col = wid * 32 + n * 16 + fr;
        #pragma unroll
        for (int q = 0; q < 4; ++q)
            out[OUT_XHAT + (size_t)(row0 + fq * 4 + q) * DIM + col] = xa[n][q] + bg2v;
    }
}

// ---------------------------------------------------------------------------
extern "C" void kernel_launch(void* const* d_in, const int* in_sizes, int n_in,
                              void* d_out, int out_size, void* d_ws, size_t ws_size,
                              hipStream_t stream)
{
    const float* x      = (const float*)d_in[0];
    const float* eps    = (const float*)d_in[1];
    const float* W1     = (const float*)d_in[2];
    const float* b1     = (const float*)d_in[3];
    const float* W2     = (const float*)d_in[4];
    const float* b2     = (const float*)d_in[5];
    const float* Wmu    = (const float*)d_in[6];
    const float* bmu    = (const float*)d_in[7];
    const float* Wlv    = (const float*)d_in[8];
    const float* blv    = (const float*)d_in[9];
    const float* logits = (const float*)d_in[10];
    const float* Wf     = (const float*)d_in[11];
    const float* Wg1    = (const float*)d_in[12];
    const float* bg1    = (const float*)d_in[13];
    const float* Wg2    = (const float*)d_in[14];
    const float* bg2    = (const float*)d_in[15];
    const int*   itp    = (const int*)d_in[16];
    float* out = (float*)d_out;
    char* wsb  = (char*)d_ws;

    hipMemsetAsync(wsb + CNT_OFF, 0, 4, stream);     // reset barrier counter
    hipLaunchKernelGGL(mono_kernel, dim3(NBLK), dim3(256), 0, stream,
                       x, eps, W1, b1, W2, b2, Wmu, bmu, Wlv, blv,
                       logits, Wf, Wg1, bg1, Wg2, bg2, itp, out, wsb);
}

// Round 9
// 25.496 us; speedup vs baseline: 6.6765x; 2.0878x over previous
//
#include <hip/hip_runtime.h>
#include <math.h>

#define BATCH 8192
#define DIM   128
#define E1    256
#define E2    128
#define BRF   32     // fused: batch rows per block

// output float offsets (x_hat, adj, mu, lv concatenated)
#define OUT_XHAT 0
#define OUT_ADJ  (BATCH*DIM)                 // 1048576
#define OUT_MU   (OUT_ADJ + DIM*DIM)         // 1064960
#define OUT_LV   (OUT_MU + BATCH*DIM)        // 2113536

// workspace BYTE offsets (frag-linear bf16 weight images + small f32 blocks)
#define W1F   0u          // 32768 bf16 = 65536 B
#define W2F   65536u      // 32768 bf16
#define WMUF  131072u     // 16384 bf16 = 32768 B
#define WLVF  163840u     // 16384 bf16
#define AHF   196608u     // 16384 bf16
#define COEF  229376u     // f32[8]: a1,a3,a5,s_safe
#define VBUF  229408u     // f32[96]: v[32], bg1[32], w2[32]

typedef __attribute__((ext_vector_type(8))) short s8v;   // 8 bf16 (4 VGPR)
typedef __attribute__((ext_vector_type(4))) float f4v;   // MFMA accumulator
#define MFMA(a, b, c) __builtin_amdgcn_mfma_f32_16x16x32_bf16(a, b, c, 0, 0, 0)

__device__ __forceinline__ ushort f2bf(float f) {        // RNE f32 -> bf16
    uint u = __float_as_uint(f);
    u += 0x7fffu + ((u >> 16) & 1u);
    return (ushort)(u >> 16);
}

// ---------------------------------------------------------------------------
// Kernel 1 (prep): blocks 0-23 convert weights f32 -> fragment-linear bf16.
// Block 24: adjacency, a_hat frags, tanh-poly coefficients.
// Fragment-linear layout for a K x N matrix: frag (nt, ks) holds the 16x32
// tile cols [nt*16,+16) x rows [ks*32,+32); elem ((nt*nKs+ks)*64 + l)*8 + j
// stores W[ks*32 + (l>>4)*8 + j][nt*16 + (l&15)].
// ---------------------------------------------------------------------------
__global__ __launch_bounds__(512) void prep_kernel(
    const float* __restrict__ W1,  const float* __restrict__ W2,
    const float* __restrict__ Wmu, const float* __restrict__ Wlv,
    const float* __restrict__ logits, const float* __restrict__ Wf,
    const float* __restrict__ Wg1, const float* __restrict__ bg1,
    const float* __restrict__ Wg2, const int* __restrict__ itp,
    float* __restrict__ out, char* __restrict__ wsb)
{
    __shared__ float gsm[16384];
    __shared__ float aux[768];
    __shared__ float vsh[32];
    const int t = threadIdx.x;

    if (blockIdx.x < 24) {
        // ---------------- weight fragment conversion ----------------
        const int tid = (int)blockIdx.x * 512 + t;       // 0..12287
        const float* W; ushort* dst; int e, N_, ksLog;
        if (tid < 4096)       { W = W1;  dst = (ushort*)(wsb + W1F);  e = tid * 8;           N_ = 256; ksLog = 2; }
        else if (tid < 8192)  { W = W2;  dst = (ushort*)(wsb + W2F);  e = (tid - 4096) * 8;  N_ = 128; ksLog = 3; }
        else if (tid < 10240) { W = Wmu; dst = (ushort*)(wsb + WMUF); e = (tid - 8192) * 8;  N_ = 128; ksLog = 2; }
        else                  { W = Wlv; dst = (ushort*)(wsb + WLVF); e = (tid - 10240) * 8; N_ = 128; ksLog = 2; }
        const int frag = e >> 9, l = (e >> 3) & 63;
        const int nt = frag >> ksLog, ks = frag & ((1 << ksLog) - 1);
        const int k0 = ks * 32 + ((l >> 4) << 3);
        const int n  = (nt << 4) + (l & 15);
        uint pk[4];
        #pragma unroll
        for (int jj = 0; jj < 4; ++jj) {
            ushort lo = f2bf(W[(k0 + 2 * jj) * N_ + n]);
            ushort hi = f2bf(W[(k0 + 2 * jj + 1) * N_ + n]);
            pk[jj] = (uint)lo | ((uint)hi << 16);
        }
        *(uint4*)(dst + e) = make_uint4(pk[0], pk[1], pk[2], pk[3]);
        return;
    }

    // ---------------- graph block ----------------
    const int it = itp[0];
    {
        const int j = t & 127, rq = t >> 7;
        float dp = 0.0f;
        for (int i = rq * 32; i < rq * 32 + 32; ++i) {
            float l = logits[i * DIM + j];
            float gv = 1.0f / (1.0f + expf(-l));   // precise: threshold boundary
            if (i == j) gv = 1.0f;
            if (it > 50 && gv < 0.1f) gv = 0.0f;
            gsm[i * DIM + j] = gv;
            if (gv > 0.0f) dp += 1.0f;
        }
        aux[rq * 128 + j] = dp;                    // partial col sums (d_in)
    }
    __syncthreads();
    if (t < 128) {
        float d = aux[t] + aux[128 + t] + aux[256 + t] + aux[384 + t];
        aux[512 + t] = 1.0f / sqrtf(fmaxf(d, 1.0f));      // rin[j]
    }
    __syncthreads();
    {
        const int i = t & 127, cq = t >> 7;
        float dp = 0.0f;
        for (int c = cq * 32; c < cq * 32 + 32; ++c)
            if (gsm[i * DIM + c] > 0.0f) dp += 1.0f;
        aux[cq * 128 + i] = dp;                    // partial row sums (d_out)
    }
    __syncthreads();
    if (t < 128) {
        float d = aux[t] + aux[128 + t] + aux[256 + t] + aux[384 + t];
        aux[640 + t] = 1.0f / sqrtf(fmaxf(d, 1.0f));      // rdout[i]
    }
    __syncthreads();
    for (int p = 0; p < 32; ++p) {                 // adj out + ahat in place
        int idx = t + 512 * p;
        int i = idx >> 7, j = idx & 127;
        float gv = gsm[idx];
        out[OUT_ADJ + idx] = gv;
        gsm[idx] = gv * aux[640 + i] * aux[512 + j];
    }
    if (t < 32) {                                  // v = W_feat @ W_g1
        float acc = 0.0f;
        for (int k = 0; k < 64; ++k) acc = fmaf(Wf[k], Wg1[k * 32 + t], acc);
        vsh[t] = acc;
        float* vb = (float*)(wsb + VBUF);
        vb[t] = acc; vb[32 + t] = bg1[t]; vb[64 + t] = Wg2[t];
    }
    __syncthreads();
    {                                              // ahat fragments (K=N=128)
        ushort* ahf = (ushort*)(wsb + AHF);
        #pragma unroll
        for (int c = 0; c < 4; ++c) {
            int e = (t + c * 512) * 8;
            int frag = e >> 9, l = (e >> 3) & 63;
            int nt = frag >> 2, ks = frag & 3;
            int k0 = ks * 32 + ((l >> 4) << 3);
            int n  = (nt << 4) + (l & 15);
            uint pk[4];
            #pragma unroll
            for (int jj = 0; jj < 4; ++jj) {
                ushort lo = f2bf(gsm[(k0 + 2 * jj) * DIM + n]);
                ushort hi = f2bf(gsm[(k0 + 2 * jj + 1) * DIM + n]);
                pk[jj] = (uint)lo | ((uint)hi << 16);
            }
            *(uint4*)(ahf + e) = make_uint4(pk[0], pk[1], pk[2], pk[3]);
        }
    }
    if (t == 0) {                                  // tanh poly coefficients
        float a1 = 0, a3 = 0, a5 = 0, vmax = 0, bmax = 0;
        for (int c = 0; c < 32; ++c) {
            float v = vsh[c], w = Wg2[c], v2 = v * v;
            a1 += w * v;
            a3 -= w * v * v2 * (1.0f / 3.0f);
            a5 += w * v * v2 * v2 * (2.0f / 15.0f);
            vmax = fmaxf(vmax, fabsf(v));
            bmax = fmaxf(bmax, fabsf(bg1[c]));
        }
        float* cf = (float*)(wsb + COEF);
        cf[0] = a1; cf[1] = a3; cf[2] = a5;
        cf[3] = (bmax == 0.0f) ? 0.2f / fmaxf(vmax, 1e-30f) : -1.0f;
    }
}

// ---------------------------------------------------------------------------
// Kernel 2 (fused): per block = 32 batch rows (2 m-tiles), 512 threads =
// 8 waves; wave w owns a 16/32-col slice per layer; each B-fragment is
// register-reused across both m-tiles (2x MFMA per load vs BR=16).
// Weight L2 traffic halves (224 KB per 32 rows instead of per 16).
// ---------------------------------------------------------------------------
__global__ __launch_bounds__(512, 1) void fused_kernel(
    const float* __restrict__ x,   const float* __restrict__ eps,
    const float* __restrict__ b1,  const float* __restrict__ b2,
    const float* __restrict__ bmu, const float* __restrict__ blv,
    const float* __restrict__ bg2p,
    float* __restrict__ out, char* __restrict__ wsb)
{
    __shared__ __attribute__((aligned(16))) ushort bufA[4096]; // x/z frags  [mt][4][64][8]
    __shared__ __attribute__((aligned(16))) ushort bufB[8192]; // h1 frags [mt][8][64][8]; t in first half
    __shared__ __attribute__((aligned(16))) ushort bufC[4096]; // h2 frags  [mt][4][64][8]
    __shared__ float vls[96];

    const int t = threadIdx.x;
    const int lane = t & 63, wid = t >> 6;          // 8 waves
    const int fr = lane & 15, fq = lane >> 4;       // C/D: col=fr, rows=fq*4+q
    const int row0 = (int)blockIdx.x * BRF;

    // ---- eps prefetch in C-fragment order (HBM latency hides under encoder) ----
    float epr[2][4];
    {
        const float* eb = eps + (size_t)(row0 + fq * 4) * DIM + wid * 16 + fr;
        #pragma unroll
        for (int mt = 0; mt < 2; ++mt)
            #pragma unroll
            for (int q = 0; q < 4; ++q)
                epr[mt][q] = eb[(mt * 16 + q) * DIM];
    }

    if (t < 96) vls[t] = ((const float*)(wsb + VBUF))[t];

    // ---- stage x tile (32 rows) -> bf16 A-fragments ----
    {
        const int r = t & 31, g = (t >> 5) & 3, ks = t >> 7;
        const float* src = x + (size_t)(row0 + r) * DIM + ks * 32 + g * 8;
        float4 u0 = *(const float4*)src;
        float4 u1 = *(const float4*)(src + 4);
        uint p0 = (uint)f2bf(u0.x) | ((uint)f2bf(u0.y) << 16);
        uint p1 = (uint)f2bf(u0.z) | ((uint)f2bf(u0.w) << 16);
        uint p2 = (uint)f2bf(u1.x) | ((uint)f2bf(u1.y) << 16);
        uint p3 = (uint)f2bf(u1.z) | ((uint)f2bf(u1.w) << 16);
        *(uint4*)&bufA[(((r >> 4) * 4 + ks) * 64 + g * 16 + (r & 15)) * 8] =
            make_uint4(p0, p1, p2, p3);
    }
    __syncthreads();

    // ---- layer 1: h1 = relu(x@W1+b1), N=256; wave w -> cols [w*32,+32) ----
    {
        const ushort* w1f = (const ushort*)(wsb + W1F);
        f4v acc[2][2] = {{{0,0,0,0},{0,0,0,0}},{{0,0,0,0},{0,0,0,0}}};  // [mt][n]
        #pragma unroll
        for (int ks = 0; ks < 4; ++ks) {
            s8v a0 = *(const s8v*)&bufA[((0 * 4 + ks) * 64 + lane) * 8];
            s8v a1 = *(const s8v*)&bufA[((1 * 4 + ks) * 64 + lane) * 8];
            #pragma unroll
            for (int n = 0; n < 2; ++n) {
                s8v b = *(const s8v*)&w1f[(((2 * wid + n) * 4 + ks) * 64 + lane) * 8];
                acc[0][n] = MFMA(a0, b, acc[0][n]);
                acc[1][n] = MFMA(a1, b, acc[1][n]);
            }
        }
        #pragma unroll
        for (int n = 0; n < 2; ++n) {
            int col = (2 * wid + n) * 16 + fr;      // k-index for layer 2
            float bb = b1[col];
            #pragma unroll
            for (int mt = 0; mt < 2; ++mt) {
                int base = ((mt * 8 + (col >> 5)) * 64 + ((col >> 3) & 3) * 16) * 8 + (col & 7);
                #pragma unroll
                for (int q = 0; q < 4; ++q)
                    bufB[base + (fq * 4 + q) * 8] = f2bf(fmaxf(acc[mt][n][q] + bb, 0.0f));
            }
        }
    }
    __syncthreads();

    // ---- layer 2: h2 = relu(h1@W2+b2), K=256, N=128; wave -> cols [w*16,+16) ----
    {
        const ushort* w2f = (const ushort*)(wsb + W2F);
        f4v acc[2] = {{0,0,0,0},{0,0,0,0}};         // [mt]
        #pragma unroll
        for (int ks = 0; ks < 8; ++ks) {
            s8v a0 = *(const s8v*)&bufB[((0 * 8 + ks) * 64 + lane) * 8];
            s8v a1 = *(const s8v*)&bufB[((1 * 8 + ks) * 64 + lane) * 8];
            s8v b  = *(const s8v*)&w2f[((wid * 8 + ks) * 64 + lane) * 8];
            acc[0] = MFMA(a0, b, acc[0]);
            acc[1] = MFMA(a1, b, acc[1]);
        }
        int col = wid * 16 + fr;
        float bb = b2[col];
        #pragma unroll
        for (int mt = 0; mt < 2; ++mt) {
            int base = ((mt * 4 + (col >> 5)) * 64 + ((col >> 3) & 3) * 16) * 8 + (col & 7);
            #pragma unroll
            for (int q = 0; q < 4; ++q)
                bufC[base + (fq * 4 + q) * 8] = f2bf(fmaxf(acc[mt][q] + bb, 0.0f));
        }
    }
    __syncthreads();

    // ---- mu / lv + z (fused; z frags restaged into bufA) ----
    {
        const ushort* wmf = (const ushort*)(wsb + WMUF);
        const ushort* wlf = (const ushort*)(wsb + WLVF);
        f4v am[2] = {{0,0,0,0},{0,0,0,0}}, al[2] = {{0,0,0,0},{0,0,0,0}};
        #pragma unroll
        for (int ks = 0; ks < 4; ++ks) {
            s8v a0 = *(const s8v*)&bufC[((0 * 4 + ks) * 64 + lane) * 8];
            s8v a1 = *(const s8v*)&bufC[((1 * 4 + ks) * 64 + lane) * 8];
            int fi = ((wid * 4 + ks) * 64 + lane) * 8;
            s8v bm = *(const s8v*)&wmf[fi];
            s8v bl = *(const s8v*)&wlf[fi];
            am[0] = MFMA(a0, bm, am[0]);
            am[1] = MFMA(a1, bm, am[1]);
            al[0] = MFMA(a0, bl, al[0]);
            al[1] = MFMA(a1, bl, al[1]);
        }
        int col = wid * 16 + fr;
        float bm = bmu[col], bl = blv[col];
        #pragma unroll
        for (int mt = 0; mt < 2; ++mt) {
            int base = ((mt * 4 + (col >> 5)) * 64 + ((col >> 3) & 3) * 16) * 8 + (col & 7);
            #pragma unroll
            for (int q = 0; q < 4; ++q) {
                int grow = row0 + mt * 16 + fq * 4 + q;
                float mu = am[mt][q] + bm;
                float lv = al[mt][q] + bl;
                out[OUT_MU + grow * DIM + col] = mu;
                out[OUT_LV + grow * DIM + col] = lv;
                float z = fmaf(epr[mt][q], __expf(0.5f * lv), mu);
                bufA[base + (fq * 4 + q) * 8] = f2bf(z);   // z frags into bufA
            }
        }
    }
    __syncthreads();

    // ---- decoder: s = z@ahat ; t = P(s) ; xhat = t@ahat + bg2 ----
    const ushort* ahf = (const ushort*)(wsb + AHF);
    const float* cf = (const float*)(wsb + COEF);
    const float a1 = cf[0], a3 = cf[1], a5 = cf[2], ssafe = cf[3];

    s8v bfr[4];                                     // ahat n-tile wid, hoisted
    #pragma unroll
    for (int ks = 0; ks < 4; ++ks)
        bfr[ks] = *(const s8v*)&ahf[((wid * 4 + ks) * 64 + lane) * 8];

    f4v sa[2] = {{0,0,0,0},{0,0,0,0}};
    #pragma unroll
    for (int ks = 0; ks < 4; ++ks) {
        s8v a0 = *(const s8v*)&bufA[((0 * 4 + ks) * 64 + lane) * 8];
        s8v a1 = *(const s8v*)&bufA[((1 * 4 + ks) * 64 + lane) * 8];
        sa[0] = MFMA(a0, bfr[ks], sa[0]);
        sa[1] = MFMA(a1, bfr[ks], sa[1]);
    }
    __syncthreads();                 // bufB reads (layer 2) long done; reuse for t

    {
        int col = wid * 16 + fr;                    // k-index for xhat GEMM
        #pragma unroll
        for (int mt = 0; mt < 2; ++mt) {
            int base = ((mt * 4 + (col >> 5)) * 64 + ((col >> 3) & 3) * 16) * 8 + (col & 7);
            #pragma unroll
            for (int q = 0; q < 4; ++q) {
                float s = sa[mt][q];
                float tv;
                if (fabsf(s) < ssafe) {             // poly path (always, in practice)
                    float s2 = s * s;
                    tv = s * fmaf(s2, fmaf(s2, a5, a3), a1);
                } else {                            // exact fallback
                    tv = 0.0f;
                    for (int c = 0; c < 32; ++c)
                        tv = fmaf(vls[64 + c], tanhf(fmaf(s, vls[c], vls[32 + c])), tv);
                }
                bufB[base + (fq * 4 + q) * 8] = f2bf(tv);
            }
        }
    }
    __syncthreads();

    f4v xa[2] = {{0,0,0,0},{0,0,0,0}};
    #pragma unroll
    for (int ks = 0; ks < 4; ++ks) {
        s8v a0 = *(const s8v*)&bufB[((0 * 4 + ks) * 64 + lane) * 8];
        s8v a1 = *(const s8v*)&bufB[((1 * 4 + ks) * 64 + lane) * 8];
        xa[0] = MFMA(a0, bfr[ks], xa[0]);
        xa[1] = MFMA(a1, bfr[ks], xa[1]);
    }
    const float bg2v = bg2p[0];
    {
        int col = wid * 16 + fr;
        #pragma unroll
        for (int mt = 0; mt < 2; ++mt)
            #pragma unroll
            for (int q = 0; q < 4; ++q)
                out[OUT_XHAT + (size_t)(row0 + mt * 16 + fq * 4 + q) * DIM + col] =
                    xa[mt][q] + bg2v;
    }
}

// ---------------------------------------------------------------------------
extern "C" void kernel_launch(void* const* d_in, const int* in_sizes, int n_in,
                              void* d_out, int out_size, void* d_ws, size_t ws_size,
                              hipStream_t stream)
{
    const float* x      = (const float*)d_in[0];
    const float* eps    = (const float*)d_in[1];
    const float* W1     = (const float*)d_in[2];
    const float* b1     = (const float*)d_in[3];
    const float* W2     = (const float*)d_in[4];
    const float* b2     = (const float*)d_in[5];
    const float* Wmu    = (const float*)d_in[6];
    const float* bmu    = (const float*)d_in[7];
    const float* Wlv    = (const float*)d_in[8];
    const float* blv    = (const float*)d_in[9];
    const float* logits = (const float*)d_in[10];
    const float* Wf     = (const float*)d_in[11];
    const float* Wg1    = (const float*)d_in[12];
    const float* bg1    = (const float*)d_in[13];
    const float* Wg2    = (const float*)d_in[14];
    const float* bg2    = (const float*)d_in[15];
    const int*   itp    = (const int*)d_in[16];
    float* out = (float*)d_out;
    char* wsb  = (char*)d_ws;

    hipLaunchKernelGGL(prep_kernel, dim3(25), dim3(512), 0, stream,
                       W1, W2, Wmu, Wlv, logits, Wf, Wg1, bg1, Wg2, itp, out, wsb);
    hipLaunchKernelGGL(fused_kernel, dim3(BATCH / BRF), dim3(512), 0, stream,
                       x, eps, b1, b2, bmu, blv, bg2, out, wsb);
}